// Round 14
// baseline (36523.798 us; speedup 1.0000x reference)
//
#include <hip/hip_runtime.h>

#define TLEN 2048
#define NB   64
#define NH   256
#define NF   64
#define NCIN 16
#define NOUT 20
#define NG   8              // batch groups (sync domains)
#define GS   8              // samples per group
#define SLU  16             // hidden units per slice (block)
#define GSLAB (NH * GS)     // 2048 floats: one group's h slab [unit][sample]
#define NSLOT 8             // h ring depth

// LLC-coherent (sc1) helpers — the proven exchange medium (r3..r10).
#define HL(p)    __hip_atomic_load((p),      __ATOMIC_RELAXED, __HIP_MEMORY_SCOPE_AGENT)
#define HS(p, v) __hip_atomic_store((p), (v), __ATOMIC_RELAXED, __HIP_MEMORY_SCOPE_AGENT)

__device__ __forceinline__ float poison_f() { return __uint_as_float(0xFFFFFFFFu); }

__device__ __forceinline__ float sigf(float x) { return 1.0f / (1.0f + __expf(-x)); }
__device__ __forceinline__ float tanh_f(float x) {
    x = fminf(fmaxf(x, -15.0f), 15.0f);
    float e = __expf(2.0f * x);
    return (e - 1.0f) / (e + 1.0f);
}

// NOTE: parameter must NOT be named `w` — `xv.w` would get macro-substituted.
#define FMA4(acc, xv, ww) do { \
    acc.x = fmaf(xv.x, (ww), acc.x); \
    acc.y = fmaf(xv.y, (ww), acc.y); \
    acc.z = fmaf(xv.z, (ww), acc.z); \
    acc.w = fmaf(xv.w, (ww), acc.w); } while (0)

#define RED32(vv) do { \
    vv.x += __shfl_xor(vv.x, 32); vv.y += __shfl_xor(vv.y, 32); \
    vv.z += __shfl_xor(vv.z, 32); vv.w += __shfl_xor(vv.w, 32); } while (0)

// ---------------- Pass A: conv + relu, per-(f, t-quarter) partial sums for BN stats
__global__ __launch_bounds__(256) void conv_stats_kernel(
    const float* __restrict__ x, const float* __restrict__ cw, const float* __restrict__ cb,
    float* __restrict__ partials)
{
    const int blk = blockIdx.x;          // 256 blocks
    const int f = blk >> 2, tq = blk & 3;
    const int tid = threadIdx.x;

    float w[NCIN][3];
#pragma unroll
    for (int c = 0; c < NCIN; ++c) {
        w[c][0] = cw[(f * NCIN + c) * 3 + 0];
        w[c][1] = cw[(f * NCIN + c) * 3 + 1];
        w[c][2] = cw[(f * NCIN + c) * 3 + 2];
    }
    const float bias = cb[f];
    float s = 0.f, s2 = 0.f;

    for (int i = 0; i < 128; ++i) {
        int idx = tq * 32768 + i * 256 + tid;   // (B*T)/4 elements per block
        int b = idx >> 11;
        int t = idx & 2047;
        const float* xb = x + (size_t)b * NCIN * TLEN;
        float acc = bias;
#pragma unroll
        for (int c = 0; c < NCIN; ++c) {
            const float* xc = xb + (size_t)c * TLEN + t;
            float xm = (t > 0)        ? xc[-1] : 0.f;
            float x0 = xc[0];
            float xp = (t < TLEN - 1) ? xc[1]  : 0.f;
            acc = fmaf(xm, w[c][0], acc);
            acc = fmaf(x0, w[c][1], acc);
            acc = fmaf(xp, w[c][2], acc);
        }
        float y = fmaxf(acc, 0.f);
        s += y; s2 = fmaf(y, y, s2);
    }

    __shared__ float rs[256], rs2[256];
    rs[tid] = s; rs2[tid] = s2;
    __syncthreads();
    for (int off = 128; off > 0; off >>= 1) {
        if (tid < off) { rs[tid] += rs[tid + off]; rs2[tid] += rs2[tid + off]; }
        __syncthreads();
    }
    if (tid == 0) {
        partials[(f * 4 + tq) * 2 + 0] = rs[0];
        partials[(f * 4 + tq) * 2 + 1] = rs2[0];
    }
}

// ---------------- Pass B: conv + relu + BN affine, write feats[t][g][f][bl]
__global__ __launch_bounds__(256) void conv_bn_feats_kernel(
    const float* __restrict__ x, const float* __restrict__ cw, const float* __restrict__ cb,
    const float* __restrict__ gamma, const float* __restrict__ beta,
    const float* __restrict__ partials, float* __restrict__ feats)
{
    const int t = blockIdx.x;            // 2048 blocks
    const int tid = threadIdx.x;
    const int b = tid & 63, fq = tid >> 6;

    __shared__ float sc[NF], sh[NF];
    if (tid < NF) {
        int f = tid;
        float s = 0.f, s2 = 0.f;
        for (int q = 0; q < 4; ++q) {
            s  += partials[(f * 4 + q) * 2 + 0];
            s2 += partials[(f * 4 + q) * 2 + 1];
        }
        const float inv_n = 1.0f / ((float)NB * (float)TLEN);
        float mean = s * inv_n;
        float var  = s2 * inv_n - mean * mean;
        float iv   = rsqrtf(var + 1e-5f);
        float scale = gamma[f] * iv;
        sc[f] = scale;
        sh[f] = beta[f] - mean * scale;
    }
    __syncthreads();

    float xr[NCIN][3];
    const float* xb = x + (size_t)b * NCIN * TLEN;
#pragma unroll
    for (int c = 0; c < NCIN; ++c) {
        const float* xc = xb + (size_t)c * TLEN + t;
        xr[c][0] = (t > 0)        ? xc[-1] : 0.f;
        xr[c][1] = xc[0];
        xr[c][2] = (t < TLEN - 1) ? xc[1]  : 0.f;
    }

    float* ft = feats + (size_t)t * (NG * NF * GS);
    for (int fi = 0; fi < 16; ++fi) {
        int f = fq * 16 + fi;
        float acc = cb[f];
#pragma unroll
        for (int c = 0; c < NCIN; ++c) {
            acc = fmaf(xr[c][0], cw[(f * NCIN + c) * 3 + 0], acc);
            acc = fmaf(xr[c][1], cw[(f * NCIN + c) * 3 + 1], acc);
            acc = fmaf(xr[c][2], cw[(f * NCIN + c) * 3 + 2], acc);
        }
        float y = fmaxf(acc, 0.f);
        ft[((b >> 3) * NF + f) * GS + (b & 7)] = fmaf(y, sc[f], sh[f]);
    }
}

// =====================================================================
// Merged L0+L1 block (512 threads): waves 0-3 = L0 role, waves 4-7 = L1 role.
// Block-step s: L0 computes h0[s] (s<TLEN); L1 computes h1[s-1] (s>=1).
// Both need only step-(s-1) publishes: h0[s-1] (slot s&7) and h1[s-2]
// (slot (s-1)&7) -> ONE combined NaN-validate per step, 16-block domain.
// NaN-poison protocol (r10 distances):
//   h0[m] slot (m+1)&7 ; h1[v] slot (v+1)&7 ; rings pre-poisoned, slot0 zeros.
//   At step s: L0 poisons h0[s-4] (slot (s+5)&7); L1 poisons h1[s-5]
//   (slot (s+4)&7). Safety: reaching step s implies all peers finished step
//   s-1 (their publishes were validated), so readers (step <= s-2) are done.
// launch_bounds(512,1): 8 waves/CU, 256-VGPR budget -> weights fit, NO spill
// (r13's (512,2) capped VGPR at 128 and spilled everything — the one change).
// =====================================================================
__global__ __launch_bounds__(512, 1) void lstm_kernel(
    const float* __restrict__ feats,
    const float* __restrict__ wih0, const float* __restrict__ whh0,
    const float* __restrict__ bih0, const float* __restrict__ bhh0,
    const float* __restrict__ wih1, const float* __restrict__ whh1,
    const float* __restrict__ bih1, const float* __restrict__ bhh1,
    const float* __restrict__ fcw,  const float* __restrict__ fcb,
    float* h0h, float* h1h, float* __restrict__ out)
{
    __shared__ float xs_l0[(NF + NH) * GS];   // [0,512): feats ; [512,2560): h0[s-1]
    __shared__ float xs_h1[NH * GS];          // h1[s-2]
    __shared__ float red0[16 * 128], red1[16 * 128];
    __shared__ float bias0[4][SLU], bias1[4][SLU];

    const int blk = blockIdx.x, tid = threadIdx.x;
    const int g = blk >> 4, sl = blk & 15;
    const int half = tid >> 8, htid = tid & 255;
    const int jp = htid & 7;
    const int g4 = (htid >> 3) & 3;
    const int kq = htid >> 5;
    const int rowA = g4 * 256 + sl * SLU + jp;
    const int rowB = rowA + 8;

    // ---- weights -> registers
    float wa[64], wb[64];
    if (half == 0) {
#pragma unroll
        for (int kk = 0; kk < 40; ++kk) {
            int k = kq * 40 + kk;
            wa[kk] = (k < NF) ? wih0[rowA * NF + k] : whh0[rowA * NH + (k - NF)];
            wb[kk] = (k < NF) ? wih0[rowB * NF + k] : whh0[rowB * NH + (k - NF)];
        }
        if (htid < 64) {
            int gg = htid >> 4, jj = htid & 15, grow = gg * 256 + sl * SLU + jj;
            bias0[gg][jj] = bih0[grow] + bhh0[grow];
        }
    } else {
#pragma unroll
        for (int kk = 0; kk < 64; ++kk) {
            int k = kq * 64 + kk;
            wa[kk] = (k < NH) ? wih1[rowA * NH + k] : whh1[rowA * NH + (k - NH)];
            wb[kk] = (k < NH) ? wih1[rowB * NH + k] : whh1[rowB * NH + (k - NH)];
        }
        if (htid < 64) {
            int gg = htid >> 4, jj = htid & 15, grow = gg * 256 + sl * SLU + jj;
            bias1[gg][jj] = bih1[grow] + bhh1[grow];
        }
    }
    __syncthreads();

    const int fj = htid >> 3, fb = htid & 7;     // finalize mapping (htid<128)
    float c_reg = 0.f;
    const int fm = htid >> 4, fseg = htid & 15;  // FC mapping (half==1, htid<160)
    const int ffo = sl * 10 + fm;
    const int fo_o = ffo >> 3, fo_b = ffo & 7;

    for (int s = 0; s <= TLEN; ++s) {
        // ---- prefetch feats (free), combined NaN-validate of step-(s-1) publishes
        float f0 = 0.f, f1 = 0.f, hv[8];
        if (half == 0 && s < TLEN) {
            const float* fsrc = feats + ((size_t)s * NG + g) * (NF * GS);
            f0 = fsrc[htid]; f1 = fsrc[256 + htid];
        }
        const float* hp0 = h0h + ((size_t)(s & 7) * NG + g) * GSLAB + htid;        // h0[s-1]
        const float* hp1 = h1h + ((size_t)((s + 7) & 7) * NG + g) * GSLAB + htid;  // h1[s-2]
        for (;;) {
            bool bad = false;
            if (half == 0) {
#pragma unroll
                for (int i = 0; i < 8; ++i) { hv[i] = HL(hp0 + i * 256); if (hv[i] != hv[i]) bad = true; }
            } else if (s >= 1) {
#pragma unroll
                for (int i = 0; i < 8; ++i) { hv[i] = HL(hp1 + i * 256); if (hv[i] != hv[i]) bad = true; }
            }
            if (__syncthreads_count(bad) == 0) break;
            __builtin_amdgcn_s_sleep(2);
        }
        // ---- stage
        if (half == 0) {
            if (s < TLEN) { xs_l0[htid] = f0; xs_l0[256 + htid] = f1; }
#pragma unroll
            for (int i = 0; i < 8; ++i) xs_l0[512 + i * 256 + htid] = hv[i];
        } else if (s >= 1) {
#pragma unroll
            for (int i = 0; i < 8; ++i) xs_h1[i * 256 + htid] = hv[i];
        }
        __syncthreads();

        // ---- GEMMs (L0 and L1 halves co-scheduled on the same SIMDs)
        float4 aA0 = {0,0,0,0}, aA1 = {0,0,0,0}, aB0 = {0,0,0,0}, aB1 = {0,0,0,0};
        if (half == 0) {
            if (s < TLEN) {
                const float* xsk = xs_l0 + kq * (40 * GS);
#pragma unroll
                for (int kk = 0; kk < 40; ++kk) {
                    float4 x0 = *(const float4*)(xsk + kk * GS);
                    float4 x1 = *(const float4*)(xsk + kk * GS + 4);
                    float wAv = wa[kk], wBv = wb[kk];
                    FMA4(aA0, x0, wAv); FMA4(aA1, x1, wAv);
                    FMA4(aB0, x0, wBv); FMA4(aB1, x1, wBv);
                }
                RED32(aA0); RED32(aA1); RED32(aB0); RED32(aB1);
                if ((htid & 32) == 0) {
                    int gk = g4 * 4 + (htid >> 6);
                    float4* r4 = (float4*)red0;
                    r4[gk * 32 + jp * 2 + 0]       = aA0;
                    r4[gk * 32 + jp * 2 + 1]       = aA1;
                    r4[gk * 32 + (jp + 8) * 2 + 0] = aB0;
                    r4[gk * 32 + (jp + 8) * 2 + 1] = aB1;
                }
            }
        } else {
            if (s >= 1) {
                const float* xsk = (kq < 4) ? (xs_l0 + NF * GS + kq * (64 * GS))
                                            : (xs_h1 + (kq - 4) * (64 * GS));
#pragma unroll
                for (int kk = 0; kk < 64; ++kk) {
                    float4 x0 = *(const float4*)(xsk + kk * GS);
                    float4 x1 = *(const float4*)(xsk + kk * GS + 4);
                    float wAv = wa[kk], wBv = wb[kk];
                    FMA4(aA0, x0, wAv); FMA4(aA1, x1, wAv);
                    FMA4(aB0, x0, wBv); FMA4(aB1, x1, wBv);
                }
                RED32(aA0); RED32(aA1); RED32(aB0); RED32(aB1);
                if ((htid & 32) == 0) {
                    int gk = g4 * 4 + (htid >> 6);
                    float4* r4 = (float4*)red1;
                    r4[gk * 32 + jp * 2 + 0]       = aA0;
                    r4[gk * 32 + jp * 2 + 1]       = aA1;
                    r4[gk * 32 + (jp + 8) * 2 + 0] = aB0;
                    r4[gk * 32 + (jp + 8) * 2 + 1] = aB1;
                }
            }
        }
        __syncthreads();

        // ---- finalize + publish + poison ; FC rides on L1 half
        if (half == 0) {
            if (s < TLEN && htid < 128) {
                float gate[4];
#pragma unroll
                for (int gg = 0; gg < 4; ++gg) {
                    float s0 = 0.f;
#pragma unroll
                    for (int k2 = 0; k2 < 4; ++k2)
                        s0 += red0[(gg * 4 + k2) * 128 + fj * 8 + fb];
                    gate[gg] = s0 + bias0[gg][fj];
                }
                float i_ = sigf(gate[0]), f_ = sigf(gate[1]);
                float g_ = tanh_f(gate[2]), o_ = sigf(gate[3]);
                c_reg = fmaf(f_, c_reg, i_ * g_);
                float h = o_ * tanh_f(c_reg);
                HS(&h0h[((size_t)((s + 1) & 7) * NG + g) * GSLAB + sl * 128 + htid], h);
                HS(&h0h[((size_t)((s + 5) & 7) * NG + g) * GSLAB + sl * 128 + htid], poison_f());
            }
        } else {
            if (s >= 1) {
                if (htid < 128) {
                    float gate[4];
#pragma unroll
                    for (int gg = 0; gg < 4; ++gg) {
                        float s0 = 0.f;
#pragma unroll
                        for (int k2 = 0; k2 < 4; ++k2)
                            s0 += red1[(gg * 4 + k2) * 128 + fj * 8 + fb];
                        gate[gg] = s0 + bias1[gg][fj];
                    }
                    float i_ = sigf(gate[0]), f_ = sigf(gate[1]);
                    float g_ = tanh_f(gate[2]), o_ = sigf(gate[3]);
                    c_reg = fmaf(f_, c_reg, i_ * g_);
                    float h = o_ * tanh_f(c_reg);
                    HS(&h1h[((size_t)(s & 7) * NG + g) * GSLAB + sl * 128 + htid], h);
                    HS(&h1h[((size_t)((s + 4) & 7) * NG + g) * GSLAB + sl * 128 + htid], poison_f());
                }
                if (s >= 2 && htid < 160) {     // FC for t = s-2 from staged h1[s-2]
                    const float* fwr = fcw + fo_o * NH;
                    const float* xr = xs_h1 + fo_b;
                    float p = 0.f;
#pragma unroll
                    for (int i2 = 0; i2 < 16; ++i2) {
                        int e = fseg * 16 + ((fseg + i2) & 15);   // bank rotation
                        p = fmaf(fwr[e], xr[e * GS], p);
                    }
#pragma unroll
                    for (int d = 1; d < 16; d <<= 1) p += __shfl_xor(p, d, 16);
                    if (fseg == 0)
                        out[((size_t)(g * GS + fo_b) * NOUT + fo_o) * TLEN + (s - 2)] = p + fcb[fo_o];
                }
            }
        }
    }

    // ---- epilogue: FC for t = TLEN-1 (h1[TLEN-1] in slot 0, published at s=TLEN)
    {
        const float* hpl = h1h + ((size_t)0 * NG + g) * GSLAB + htid;
        float hv2[8];
        for (;;) {
            bool bad = false;
            if (half == 1) {
#pragma unroll
                for (int i = 0; i < 8; ++i) { hv2[i] = HL(hpl + i * 256); if (hv2[i] != hv2[i]) bad = true; }
            }
            if (__syncthreads_count(bad) == 0) break;
            __builtin_amdgcn_s_sleep(2);
        }
        if (half == 1) {
#pragma unroll
            for (int i = 0; i < 8; ++i) xs_h1[i * 256 + htid] = hv2[i];
        }
        __syncthreads();
        if (half == 1 && htid < 160) {
            const float* fwr = fcw + fo_o * NH;
            const float* xr = xs_h1 + fo_b;
            float p = 0.f;
#pragma unroll
            for (int i2 = 0; i2 < 16; ++i2) {
                int e = fseg * 16 + ((fseg + i2) & 15);
                p = fmaf(fwr[e], xr[e * GS], p);
            }
#pragma unroll
            for (int d = 1; d < 16; d <<= 1) p += __shfl_xor(p, d, 16);
            if (fseg == 0)
                out[((size_t)(g * GS + fo_b) * NOUT + fo_o) * TLEN + (TLEN - 1)] = p + fcb[fo_o];
        }
    }
}

extern "C" void kernel_launch(void* const* d_in, const int* in_sizes, int n_in,
                              void* d_out, int out_size, void* d_ws, size_t ws_size,
                              hipStream_t stream) {
    (void)in_sizes; (void)n_in; (void)out_size; (void)ws_size;
    const float* x      = (const float*)d_in[0];
    const float* conv_w = (const float*)d_in[1];
    const float* conv_b = (const float*)d_in[2];
    const float* gamma  = (const float*)d_in[3];
    const float* beta   = (const float*)d_in[4];
    const float* wih0   = (const float*)d_in[5];
    const float* whh0   = (const float*)d_in[6];
    const float* bih0   = (const float*)d_in[7];
    const float* bhh0   = (const float*)d_in[8];
    const float* wih1   = (const float*)d_in[9];
    const float* whh1   = (const float*)d_in[10];
    const float* bih1   = (const float*)d_in[11];
    const float* bhh1   = (const float*)d_in[12];
    const float* fcw    = (const float*)d_in[13];
    const float* fcb    = (const float*)d_in[14];
    float* out = (float*)d_out;

    char* ws = (char*)d_ws;
    const size_t H_RING  = (size_t)NSLOT * NG * GSLAB * 4;       // 524,288 B each
    const size_t SLOT0_B = (size_t)NG * GSLAB * 4;               // 65,536 B
    const size_t FEATS_B = (size_t)TLEN * NG * NF * GS * 4;      // 33,554,432 B

    float* h0h      = (float*)(ws);
    float* h1h      = (float*)(ws + H_RING);
    float* feats    = (float*)(ws + 2 * H_RING);
    float* partials = (float*)(ws + 2 * H_RING + FEATS_B);

    // Poison rings with 0xFF (= NaN), then zero slot 0 (h[-1]).
    (void)hipMemsetAsync(h0h, 0xFF, H_RING, stream);
    (void)hipMemsetAsync(h1h, 0xFF, H_RING, stream);
    (void)hipMemsetAsync(h0h, 0x00, SLOT0_B, stream);
    (void)hipMemsetAsync(h1h, 0x00, SLOT0_B, stream);

    conv_stats_kernel<<<dim3(256), dim3(256), 0, stream>>>(x, conv_w, conv_b, partials);
    conv_bn_feats_kernel<<<dim3(2048), dim3(256), 0, stream>>>(
        x, conv_w, conv_b, gamma, beta, partials, feats);

    lstm_kernel<<<dim3(128), dim3(512), 0, stream>>>(
        feats, wih0, whh0, bih0, bhh0, wih1, whh1, bih1, bhh1,
        fcw, fcb, h0h, h1h, out);
}

// Round 15
// 12498.963 us; speedup vs baseline: 2.9221x; 2.9221x over previous
//
#include <hip/hip_runtime.h>

#define TLEN 2048
#define NB   64
#define NH   256
#define NF   64
#define NCIN 16
#define NOUT 20
#define NG   8              // batch groups (sync domains)
#define GS   8              // samples per group
#define SLU  16             // hidden units per slice (block)
#define GSLAB (NH * GS)     // 2048 floats: one group's h slab [unit][sample]
#define NSLOT 8             // h ring depth

// LLC-coherent (sc1) helpers — the proven exchange medium (r3..r10).
#define HL(p)    __hip_atomic_load((p),      __ATOMIC_RELAXED, __HIP_MEMORY_SCOPE_AGENT)
#define HS(p, v) __hip_atomic_store((p), (v), __ATOMIC_RELAXED, __HIP_MEMORY_SCOPE_AGENT)

__device__ __forceinline__ float poison_f() { return __uint_as_float(0xFFFFFFFFu); }

__device__ __forceinline__ float sigf(float x) { return 1.0f / (1.0f + __expf(-x)); }
__device__ __forceinline__ float tanh_f(float x) {
    x = fminf(fmaxf(x, -15.0f), 15.0f);
    float e = __expf(2.0f * x);
    return (e - 1.0f) / (e + 1.0f);
}

// NOTE: parameter must NOT be named `w` — `xv.w` would get macro-substituted.
#define FMA4(acc, xv, ww) do { \
    acc.x = fmaf(xv.x, (ww), acc.x); \
    acc.y = fmaf(xv.y, (ww), acc.y); \
    acc.z = fmaf(xv.z, (ww), acc.z); \
    acc.w = fmaf(xv.w, (ww), acc.w); } while (0)

#define RED32(vv) do { \
    vv.x += __shfl_xor(vv.x, 32); vv.y += __shfl_xor(vv.y, 32); \
    vv.z += __shfl_xor(vv.z, 32); vv.w += __shfl_xor(vv.w, 32); } while (0)

// ---------------- Pass A: conv + relu, per-(f, t-quarter) partial sums for BN stats
__global__ __launch_bounds__(256) void conv_stats_kernel(
    const float* __restrict__ x, const float* __restrict__ cw, const float* __restrict__ cb,
    float* __restrict__ partials)
{
    const int blk = blockIdx.x;          // 256 blocks
    const int f = blk >> 2, tq = blk & 3;
    const int tid = threadIdx.x;

    float w[NCIN][3];
#pragma unroll
    for (int c = 0; c < NCIN; ++c) {
        w[c][0] = cw[(f * NCIN + c) * 3 + 0];
        w[c][1] = cw[(f * NCIN + c) * 3 + 1];
        w[c][2] = cw[(f * NCIN + c) * 3 + 2];
    }
    const float bias = cb[f];
    float s = 0.f, s2 = 0.f;

    for (int i = 0; i < 128; ++i) {
        int idx = tq * 32768 + i * 256 + tid;   // (B*T)/4 elements per block
        int b = idx >> 11;
        int t = idx & 2047;
        const float* xb = x + (size_t)b * NCIN * TLEN;
        float acc = bias;
#pragma unroll
        for (int c = 0; c < NCIN; ++c) {
            const float* xc = xb + (size_t)c * TLEN + t;
            float xm = (t > 0)        ? xc[-1] : 0.f;
            float x0 = xc[0];
            float xp = (t < TLEN - 1) ? xc[1]  : 0.f;
            acc = fmaf(xm, w[c][0], acc);
            acc = fmaf(x0, w[c][1], acc);
            acc = fmaf(xp, w[c][2], acc);
        }
        float y = fmaxf(acc, 0.f);
        s += y; s2 = fmaf(y, y, s2);
    }

    __shared__ float rs[256], rs2[256];
    rs[tid] = s; rs2[tid] = s2;
    __syncthreads();
    for (int off = 128; off > 0; off >>= 1) {
        if (tid < off) { rs[tid] += rs[tid + off]; rs2[tid] += rs2[tid + off]; }
        __syncthreads();
    }
    if (tid == 0) {
        partials[(f * 4 + tq) * 2 + 0] = rs[0];
        partials[(f * 4 + tq) * 2 + 1] = rs2[0];
    }
}

// ---------------- Pass B: conv + relu + BN affine, write feats[t][g][f][bl]
__global__ __launch_bounds__(256) void conv_bn_feats_kernel(
    const float* __restrict__ x, const float* __restrict__ cw, const float* __restrict__ cb,
    const float* __restrict__ gamma, const float* __restrict__ beta,
    const float* __restrict__ partials, float* __restrict__ feats)
{
    const int t = blockIdx.x;            // 2048 blocks
    const int tid = threadIdx.x;
    const int b = tid & 63, fq = tid >> 6;

    __shared__ float sc[NF], sh[NF];
    if (tid < NF) {
        int f = tid;
        float s = 0.f, s2 = 0.f;
        for (int q = 0; q < 4; ++q) {
            s  += partials[(f * 4 + q) * 2 + 0];
            s2 += partials[(f * 4 + q) * 2 + 1];
        }
        const float inv_n = 1.0f / ((float)NB * (float)TLEN);
        float mean = s * inv_n;
        float var  = s2 * inv_n - mean * mean;
        float iv   = rsqrtf(var + 1e-5f);
        float scale = gamma[f] * iv;
        sc[f] = scale;
        sh[f] = beta[f] - mean * scale;
    }
    __syncthreads();

    float xr[NCIN][3];
    const float* xb = x + (size_t)b * NCIN * TLEN;
#pragma unroll
    for (int c = 0; c < NCIN; ++c) {
        const float* xc = xb + (size_t)c * TLEN + t;
        xr[c][0] = (t > 0)        ? xc[-1] : 0.f;
        xr[c][1] = xc[0];
        xr[c][2] = (t < TLEN - 1) ? xc[1]  : 0.f;
    }

    float* ft = feats + (size_t)t * (NG * NF * GS);
    for (int fi = 0; fi < 16; ++fi) {
        int f = fq * 16 + fi;
        float acc = cb[f];
#pragma unroll
        for (int c = 0; c < NCIN; ++c) {
            acc = fmaf(xr[c][0], cw[(f * NCIN + c) * 3 + 0], acc);
            acc = fmaf(xr[c][1], cw[(f * NCIN + c) * 3 + 1], acc);
            acc = fmaf(xr[c][2], cw[(f * NCIN + c) * 3 + 2], acc);
        }
        float y = fmaxf(acc, 0.f);
        ft[((b >> 3) * NF + f) * GS + (b & 7)] = fmaf(y, sc[f], sh[f]);
    }
}

// =====================================================================
// r10 protocol EXACTLY (256 slice-blocks, NaN-poison rings) with a
// 512-thread / 16-way-K decomposition so per-thread weights fit the
// 512-thread-block 128-VGPR cap (r13/r14 lesson) while giving 2 waves/SIMD.
//   thread map: jp = tid&7 (unit pair), g4 = (tid>>3)&3 (gate), kq = tid>>5 (0..15)
//   L0: wa[20]+wb[20] ; L1: wa[32]+wb[32]  -> ~110-120 VGPR total, no spill at 128.
//   reduction: shfl_xor(32) pairs kq(2w,2w+1) -> 8 wave-partials -> LDS tree.
// Protocol (r10): h[m] in slot (m+1)&7; rings pre-poisoned; slot0 zeros;
//   L0 at step s poisons h0[s-4]; L1 poisons h1[s-4]; L0 sentinel on h1[s-3].
// =====================================================================

// ---------------- layer-0 block (slice sl of group g), 512 threads
__device__ __forceinline__ void run_l0(
    int g, int sl, int tid,
    const float* __restrict__ feats,
    const float* __restrict__ wih, const float* __restrict__ whh,
    const float* __restrict__ bih, const float* __restrict__ bhh,
    float* h0, const float* h1,
    float* xs, float* red, float (*biasS)[SLU])
{
    constexpr int KT = 320 / 16;          // 20 ks per thread
    const int jp = tid & 7;
    const int g4 = (tid >> 3) & 3;
    const int kq = tid >> 5;              // 0..15
    const int rowA = g4 * 256 + sl * SLU + jp;
    const int rowB = rowA + 8;

    float wa[KT], wb[KT];
#pragma unroll
    for (int kk = 0; kk < KT; ++kk) {
        int k = kq * KT + kk;
        wa[kk] = (k < NF) ? wih[rowA * NF + k] : whh[rowA * NH + (k - NF)];
        wb[kk] = (k < NF) ? wih[rowB * NF + k] : whh[rowB * NH + (k - NF)];
    }
    if (tid < 64) {
        int gg = tid >> 4, jj = tid & 15, grow = gg * 256 + sl * SLU + jj;
        biasS[gg][jj] = bih[grow] + bhh[grow];
    }
    __syncthreads();

    const int fj = (tid & 127) >> 3, fb = tid & 7;   // finalize mapping (tid<128)
    float c_reg = 0.f;
    const int sj = (tid >= 128 && tid < 144) ? tid - 128 : 0;   // sentinel slice id

    for (int s = 0; s < TLEN; ++s) {
        const float* fsrc = feats + ((size_t)s * NG + g) * (NF * GS);
        float f0 = fsrc[tid];                                    // 512 floats, 1/thread
        const float* hp   = h0 + ((size_t)(s & 7) * NG + g) * GSLAB + tid;
        const float* sent = h1 + ((size_t)((s + 6) & 7) * NG + g) * GSLAB + sj * 128;
        float hv[4];
        for (;;) {
            bool bad = false;
#pragma unroll
            for (int i = 0; i < 4; ++i) { hv[i] = HL(hp + i * 512); if (hv[i] != hv[i]) bad = true; }
            if (s >= 3 && tid >= 128 && tid < 144) {
                float sv = HL(sent); if (sv != sv) bad = true;
            }
            if (__syncthreads_count(bad) == 0) break;
            __builtin_amdgcn_s_sleep(2);
        }
        xs[tid] = f0;
#pragma unroll
        for (int i = 0; i < 4; ++i) xs[512 + i * 512 + tid] = hv[i];
        __syncthreads();

        // gate GEMM, KT=20
        float4 aA0 = {0,0,0,0}, aA1 = {0,0,0,0}, aB0 = {0,0,0,0}, aB1 = {0,0,0,0};
        const float* xsk = xs + kq * (KT * GS);
#pragma unroll
        for (int kk = 0; kk < KT; ++kk) {
            float4 x0 = *(const float4*)(xsk + kk * GS);
            float4 x1 = *(const float4*)(xsk + kk * GS + 4);
            float wAv = wa[kk], wBv = wb[kk];
            FMA4(aA0, x0, wAv); FMA4(aA1, x1, wAv);
            FMA4(aB0, x0, wBv); FMA4(aB1, x1, wBv);
        }
        RED32(aA0); RED32(aA1); RED32(aB0); RED32(aB1);
        if ((tid & 32) == 0) {
            int gk = g4 * 8 + (tid >> 6);          // [gate][kq-pair 0..7]
            float4* r4 = (float4*)red;
            r4[gk * 32 + jp * 2 + 0]       = aA0;
            r4[gk * 32 + jp * 2 + 1]       = aA1;
            r4[gk * 32 + (jp + 8) * 2 + 0] = aB0;
            r4[gk * 32 + (jp + 8) * 2 + 1] = aB1;
        }
        __syncthreads();

        if (tid < 128) {
            float gate[4];
#pragma unroll
            for (int gg = 0; gg < 4; ++gg) {
                float s0 = 0.f;
#pragma unroll
                for (int k2 = 0; k2 < 8; ++k2)
                    s0 += red[(gg * 8 + k2) * 128 + fj * 8 + fb];
                gate[gg] = s0 + biasS[gg][fj];
            }
            float i_ = sigf(gate[0]), f_ = sigf(gate[1]);
            float g_ = tanh_f(gate[2]), o_ = sigf(gate[3]);
            c_reg = fmaf(f_, c_reg, i_ * g_);
            float h = o_ * tanh_f(c_reg);
            HS(&h0[((size_t)((s + 1) & 7) * NG + g) * GSLAB + sl * 128 + tid], h);
            HS(&h0[((size_t)((s + 5) & 7) * NG + g) * GSLAB + sl * 128 + tid], poison_f());
        }
    }
}

// ---------------- layer-1 block (slice sl of group g), FC fused, 512 threads
__device__ __forceinline__ void run_l1(
    int g, int sl, int tid,
    const float* __restrict__ h0,
    const float* __restrict__ wih, const float* __restrict__ whh,
    const float* __restrict__ bih, const float* __restrict__ bhh,
    const float* __restrict__ fcw, const float* __restrict__ fcb,
    float* h1, float* __restrict__ out,
    float* xs, float* red, float (*biasS)[SLU])
{
    constexpr int KT = 512 / 16;          // 32 ks per thread
    const int jp = tid & 7;
    const int g4 = (tid >> 3) & 3;
    const int kq = tid >> 5;              // 0..15
    const int rowA = g4 * 256 + sl * SLU + jp;
    const int rowB = rowA + 8;

    float wa[KT], wb[KT];
#pragma unroll
    for (int kk = 0; kk < KT; ++kk) {
        int k = kq * KT + kk;
        wa[kk] = (k < NH) ? wih[rowA * NH + k] : whh[rowA * NH + (k - NH)];
        wb[kk] = (k < NH) ? wih[rowB * NH + k] : whh[rowB * NH + (k - NH)];
    }
    if (tid < 64) {
        int gg = tid >> 4, jj = tid & 15, grow = gg * 256 + sl * SLU + jj;
        biasS[gg][jj] = bih[grow] + bhh[grow];
    }
    __syncthreads();

    const int fj = (tid & 127) >> 3, fb = tid & 7;
    float c_reg = 0.f;
    const int fm = tid >> 4, fseg = tid & 15;     // FC mapping (tid<160)
    const int ffo = sl * 10 + (fm < 10 ? fm : 0);
    const int fo_o = ffo >> 3, fo_b = ffo & 7;

    for (int s = 0; s < TLEN; ++s) {
        // h0[s] in slot (s+1)&7 ; h1[s-1] in slot s&7
        const float* h0c = h0 + ((size_t)((s + 1) & 7) * NG + g) * GSLAB + tid;
        const float* h1p = h1 + ((size_t)(s & 7) * NG + g) * GSLAB + tid;
        float xr0[4], xr1[4];
        for (;;) {
            bool bad = false;
#pragma unroll
            for (int i = 0; i < 4; ++i) { xr0[i] = HL(h0c + i * 512); if (xr0[i] != xr0[i]) bad = true; }
#pragma unroll
            for (int i = 0; i < 4; ++i) { xr1[i] = HL(h1p + i * 512); if (xr1[i] != xr1[i]) bad = true; }
            if (__syncthreads_count(bad) == 0) break;
            __builtin_amdgcn_s_sleep(2);
        }
#pragma unroll
        for (int i = 0; i < 4; ++i) xs[i * 512 + tid] = xr0[i];
#pragma unroll
        for (int i = 0; i < 4; ++i) xs[2048 + i * 512 + tid] = xr1[i];
        __syncthreads();

        // gate GEMM, KT=32: kq 0..7 read h0 (xs[0,2048)), kq 8..15 read h1
        float4 aA0 = {0,0,0,0}, aA1 = {0,0,0,0}, aB0 = {0,0,0,0}, aB1 = {0,0,0,0};
        const float* xsk = xs + kq * (KT * GS);
#pragma unroll
        for (int kk = 0; kk < KT; ++kk) {
            float4 x0 = *(const float4*)(xsk + kk * GS);
            float4 x1 = *(const float4*)(xsk + kk * GS + 4);
            float wAv = wa[kk], wBv = wb[kk];
            FMA4(aA0, x0, wAv); FMA4(aA1, x1, wAv);
            FMA4(aB0, x0, wBv); FMA4(aB1, x1, wBv);
        }
        RED32(aA0); RED32(aA1); RED32(aB0); RED32(aB1);
        if ((tid & 32) == 0) {
            int gk = g4 * 8 + (tid >> 6);
            float4* r4 = (float4*)red;
            r4[gk * 32 + jp * 2 + 0]       = aA0;
            r4[gk * 32 + jp * 2 + 1]       = aA1;
            r4[gk * 32 + (jp + 8) * 2 + 0] = aB0;
            r4[gk * 32 + (jp + 8) * 2 + 1] = aB1;
        }
        __syncthreads();

        if (tid < 128) {
            float gate[4];
#pragma unroll
            for (int gg = 0; gg < 4; ++gg) {
                float s0 = 0.f;
#pragma unroll
                for (int k2 = 0; k2 < 8; ++k2)
                    s0 += red[(gg * 8 + k2) * 128 + fj * 8 + fb];
                gate[gg] = s0 + biasS[gg][fj];
            }
            float i_ = sigf(gate[0]), f_ = sigf(gate[1]);
            float g_ = tanh_f(gate[2]), o_ = sigf(gate[3]);
            c_reg = fmaf(f_, c_reg, i_ * g_);
            float h = o_ * tanh_f(c_reg);
            HS(&h1[((size_t)((s + 1) & 7) * NG + g) * GSLAB + sl * 128 + tid], h);
            HS(&h1[((size_t)((s + 5) & 7) * NG + g) * GSLAB + sl * 128 + tid], poison_f());
        }

        // FC for t = s-1 from staged h1prev (xs[2048..]); shuffle-reduce
        if (s >= 1 && tid < 160) {
            const float* fwr = fcw + fo_o * NH;
            const float* xr = xs + NH * GS + fo_b;
            float p = 0.f;
#pragma unroll
            for (int i2 = 0; i2 < 16; ++i2) {
                int e = fseg * 16 + ((fseg + i2) & 15);   // bank rotation
                p = fmaf(fwr[e], xr[e * GS], p);
            }
#pragma unroll
            for (int d = 1; d < 16; d <<= 1) p += __shfl_xor(p, d, 16);
            if (fseg == 0)
                out[((size_t)(g * GS + fo_b) * NOUT + fo_o) * TLEN + (s - 1)] = p + fcb[fo_o];
        }
        __syncthreads();   // protect xs before next step's staging
    }

    // epilogue FC for t = TLEN-1: validate-load h1[TLEN-1] (slot 0)
    {
        const float* hlast = h1 + ((size_t)(TLEN & 7) * NG + g) * GSLAB + tid;
        float xr1[4];
        for (;;) {
            bool bad = false;
#pragma unroll
            for (int i = 0; i < 4; ++i) { xr1[i] = HL(hlast + i * 512); if (xr1[i] != xr1[i]) bad = true; }
            if (__syncthreads_count(bad) == 0) break;
            __builtin_amdgcn_s_sleep(2);
        }
#pragma unroll
        for (int i = 0; i < 4; ++i) xs[2048 + i * 512 + tid] = xr1[i];
        __syncthreads();
        if (tid < 160) {
            const float* fwr = fcw + fo_o * NH;
            const float* xr = xs + NH * GS + fo_b;
            float p = 0.f;
#pragma unroll
            for (int i2 = 0; i2 < 16; ++i2) {
                int e = fseg * 16 + ((fseg + i2) & 15);
                p = fmaf(fwr[e], xr[e * GS], p);
            }
#pragma unroll
            for (int d = 1; d < 16; d <<= 1) p += __shfl_xor(p, d, 16);
            if (fseg == 0)
                out[((size_t)(g * GS + fo_b) * NOUT + fo_o) * TLEN + (TLEN - 1)] = p + fcb[fo_o];
        }
    }
}

// Grid: 256 blocks x 512 threads, plain launch. Block (g, r): r<16 -> L0 slice r;
// r>=16 -> L1 slice r-16. 128-VGPR cap (512-thread block) is the DESIGN budget.
__global__ __launch_bounds__(512, 1) void lstm_kernel(
    const float* __restrict__ feats,
    const float* __restrict__ wih0, const float* __restrict__ whh0,
    const float* __restrict__ bih0, const float* __restrict__ bhh0,
    const float* __restrict__ wih1, const float* __restrict__ whh1,
    const float* __restrict__ bih1, const float* __restrict__ bhh1,
    const float* __restrict__ fcw,  const float* __restrict__ fcb,
    float* h0h, float* h1h, float* __restrict__ out)
{
    __shared__ float xs[512 * GS];        // 16 KB
    __shared__ float red[32 * 128];       // 16 KB (8 wave-partials x 4 gates)
    __shared__ float biasS[4][SLU];
    const int blk = blockIdx.x, tid = threadIdx.x;
    const int g = blk >> 5, r = blk & 31;

    if (r < 16)
        run_l0(g, r, tid, feats, wih0, whh0, bih0, bhh0,
               h0h, h1h, xs, red, biasS);
    else
        run_l1(g, r - 16, tid, h0h, wih1, whh1, bih1, bhh1,
               fcw, fcb, h1h, out, xs, red, biasS);
}

extern "C" void kernel_launch(void* const* d_in, const int* in_sizes, int n_in,
                              void* d_out, int out_size, void* d_ws, size_t ws_size,
                              hipStream_t stream) {
    (void)in_sizes; (void)n_in; (void)out_size; (void)ws_size;
    const float* x      = (const float*)d_in[0];
    const float* conv_w = (const float*)d_in[1];
    const float* conv_b = (const float*)d_in[2];
    const float* gamma  = (const float*)d_in[3];
    const float* beta   = (const float*)d_in[4];
    const float* wih0   = (const float*)d_in[5];
    const float* whh0   = (const float*)d_in[6];
    const float* bih0   = (const float*)d_in[7];
    const float* bhh0   = (const float*)d_in[8];
    const float* wih1   = (const float*)d_in[9];
    const float* whh1   = (const float*)d_in[10];
    const float* bih1   = (const float*)d_in[11];
    const float* bhh1   = (const float*)d_in[12];
    const float* fcw    = (const float*)d_in[13];
    const float* fcb    = (const float*)d_in[14];
    float* out = (float*)d_out;

    char* ws = (char*)d_ws;
    const size_t H_RING  = (size_t)NSLOT * NG * GSLAB * 4;       // 524,288 B each
    const size_t SLOT0_B = (size_t)NG * GSLAB * 4;               // 65,536 B
    const size_t FEATS_B = (size_t)TLEN * NG * NF * GS * 4;      // 33,554,432 B

    float* h0h      = (float*)(ws);
    float* h1h      = (float*)(ws + H_RING);
    float* feats    = (float*)(ws + 2 * H_RING);
    float* partials = (float*)(ws + 2 * H_RING + FEATS_B);

    // Poison rings with 0xFF (= NaN), then zero slot 0 (h[-1]).
    (void)hipMemsetAsync(h0h, 0xFF, H_RING, stream);
    (void)hipMemsetAsync(h1h, 0xFF, H_RING, stream);
    (void)hipMemsetAsync(h0h, 0x00, SLOT0_B, stream);
    (void)hipMemsetAsync(h1h, 0x00, SLOT0_B, stream);

    conv_stats_kernel<<<dim3(256), dim3(256), 0, stream>>>(x, conv_w, conv_b, partials);
    conv_bn_feats_kernel<<<dim3(2048), dim3(256), 0, stream>>>(
        x, conv_w, conv_b, gamma, beta, partials, feats);

    lstm_kernel<<<dim3(256), dim3(512), 0, stream>>>(
        feats, wih0, whh0, bih0, bhh0, wih1, whh1, bih1, bhh1,
        fcw, fcb, h0h, h1h, out);
}

// Round 16
// 11864.021 us; speedup vs baseline: 3.0785x; 1.0535x over previous
//
#include <hip/hip_runtime.h>

#define TLEN 2048
#define NB   64
#define NH   256
#define NF   64
#define NCIN 16
#define NOUT 20
#define NG   8              // batch groups (sync domains)
#define GS   8              // samples per group
#define SLU  16             // hidden units per slice (block)
#define GSLAB (NH * GS)     // 2048 floats: one group's h slab [unit][sample]
#define NSLOT 8             // h ring depth

// LLC-coherent (sc1) helpers — the proven exchange medium (r3..r15).
#define HL(p)    __hip_atomic_load((p),      __ATOMIC_RELAXED, __HIP_MEMORY_SCOPE_AGENT)
#define HS(p, v) __hip_atomic_store((p), (v), __ATOMIC_RELAXED, __HIP_MEMORY_SCOPE_AGENT)

__device__ __forceinline__ float poison_f() { return __uint_as_float(0xFFFFFFFFu); }

__device__ __forceinline__ float sigf(float x) { return 1.0f / (1.0f + __expf(-x)); }
__device__ __forceinline__ float tanh_f(float x) {
    x = fminf(fmaxf(x, -15.0f), 15.0f);
    float e = __expf(2.0f * x);
    return (e - 1.0f) / (e + 1.0f);
}

// NOTE: parameter must NOT be named `w` — `xv.w` would get macro-substituted.
#define FMA4(acc, xv, ww) do { \
    acc.x = fmaf(xv.x, (ww), acc.x); \
    acc.y = fmaf(xv.y, (ww), acc.y); \
    acc.z = fmaf(xv.z, (ww), acc.z); \
    acc.w = fmaf(xv.w, (ww), acc.w); } while (0)

#define RED32(vv) do { \
    vv.x += __shfl_xor(vv.x, 32); vv.y += __shfl_xor(vv.y, 32); \
    vv.z += __shfl_xor(vv.z, 32); vv.w += __shfl_xor(vv.w, 32); } while (0)

// ---------------- Pass A: conv + relu, per-(f, t-quarter) partial sums for BN stats
__global__ __launch_bounds__(256) void conv_stats_kernel(
    const float* __restrict__ x, const float* __restrict__ cw, const float* __restrict__ cb,
    float* __restrict__ partials)
{
    const int blk = blockIdx.x;          // 256 blocks
    const int f = blk >> 2, tq = blk & 3;
    const int tid = threadIdx.x;

    float w[NCIN][3];
#pragma unroll
    for (int c = 0; c < NCIN; ++c) {
        w[c][0] = cw[(f * NCIN + c) * 3 + 0];
        w[c][1] = cw[(f * NCIN + c) * 3 + 1];
        w[c][2] = cw[(f * NCIN + c) * 3 + 2];
    }
    const float bias = cb[f];
    float s = 0.f, s2 = 0.f;

    for (int i = 0; i < 128; ++i) {
        int idx = tq * 32768 + i * 256 + tid;   // (B*T)/4 elements per block
        int b = idx >> 11;
        int t = idx & 2047;
        const float* xb = x + (size_t)b * NCIN * TLEN;
        float acc = bias;
#pragma unroll
        for (int c = 0; c < NCIN; ++c) {
            const float* xc = xb + (size_t)c * TLEN + t;
            float xm = (t > 0)        ? xc[-1] : 0.f;
            float x0 = xc[0];
            float xp = (t < TLEN - 1) ? xc[1]  : 0.f;
            acc = fmaf(xm, w[c][0], acc);
            acc = fmaf(x0, w[c][1], acc);
            acc = fmaf(xp, w[c][2], acc);
        }
        float y = fmaxf(acc, 0.f);
        s += y; s2 = fmaf(y, y, s2);
    }

    __shared__ float rs[256], rs2[256];
    rs[tid] = s; rs2[tid] = s2;
    __syncthreads();
    for (int off = 128; off > 0; off >>= 1) {
        if (tid < off) { rs[tid] += rs[tid + off]; rs2[tid] += rs2[tid + off]; }
        __syncthreads();
    }
    if (tid == 0) {
        partials[(f * 4 + tq) * 2 + 0] = rs[0];
        partials[(f * 4 + tq) * 2 + 1] = rs2[0];
    }
}

// ---------------- Pass B: conv + relu + BN affine, write feats[t][g][f][bl]
__global__ __launch_bounds__(256) void conv_bn_feats_kernel(
    const float* __restrict__ x, const float* __restrict__ cw, const float* __restrict__ cb,
    const float* __restrict__ gamma, const float* __restrict__ beta,
    const float* __restrict__ partials, float* __restrict__ feats)
{
    const int t = blockIdx.x;            // 2048 blocks
    const int tid = threadIdx.x;
    const int b = tid & 63, fq = tid >> 6;

    __shared__ float sc[NF], sh[NF];
    if (tid < NF) {
        int f = tid;
        float s = 0.f, s2 = 0.f;
        for (int q = 0; q < 4; ++q) {
            s  += partials[(f * 4 + q) * 2 + 0];
            s2 += partials[(f * 4 + q) * 2 + 1];
        }
        const float inv_n = 1.0f / ((float)NB * (float)TLEN);
        float mean = s * inv_n;
        float var  = s2 * inv_n - mean * mean;
        float iv   = rsqrtf(var + 1e-5f);
        float scale = gamma[f] * iv;
        sc[f] = scale;
        sh[f] = beta[f] - mean * scale;
    }
    __syncthreads();

    float xr[NCIN][3];
    const float* xb = x + (size_t)b * NCIN * TLEN;
#pragma unroll
    for (int c = 0; c < NCIN; ++c) {
        const float* xc = xb + (size_t)c * TLEN + t;
        xr[c][0] = (t > 0)        ? xc[-1] : 0.f;
        xr[c][1] = xc[0];
        xr[c][2] = (t < TLEN - 1) ? xc[1]  : 0.f;
    }

    float* ft = feats + (size_t)t * (NG * NF * GS);
    for (int fi = 0; fi < 16; ++fi) {
        int f = fq * 16 + fi;
        float acc = cb[f];
#pragma unroll
        for (int c = 0; c < NCIN; ++c) {
            acc = fmaf(xr[c][0], cw[(f * NCIN + c) * 3 + 0], acc);
            acc = fmaf(xr[c][1], cw[(f * NCIN + c) * 3 + 1], acc);
            acc = fmaf(xr[c][2], cw[(f * NCIN + c) * 3 + 2], acc);
        }
        float y = fmaxf(acc, 0.f);
        ft[((b >> 3) * NF + f) * GS + (b & 7)] = fmaf(y, sc[f], sh[f]);
    }
}

// =====================================================================
// r15 structure (256 slice-blocks x 512 threads, 16-way K, NaN-poison rings)
// with PER-THREAD NaN spins (r16): each thread spins only on its own values,
// then ONE __syncthreads (barrier A) — no barrier-per-poll-iteration.
// Safety: barrier A still implies collective validation (all threads passed
// their spins), and all poisons occur after barrier A, so every r10/r15
// poison-distance argument holds unchanged.
// Protocol: h[m] in slot (m+1)&7; rings pre-poisoned; slot0 zeros;
//   L0 at step s poisons h0[s-4]; L1 poisons h1[s-4]; L0 sentinel on h1[s-3].
// =====================================================================

// ---------------- layer-0 block (slice sl of group g), 512 threads
__device__ __forceinline__ void run_l0(
    int g, int sl, int tid,
    const float* __restrict__ feats,
    const float* __restrict__ wih, const float* __restrict__ whh,
    const float* __restrict__ bih, const float* __restrict__ bhh,
    float* h0, const float* h1,
    float* xs, float* red, float (*biasS)[SLU])
{
    constexpr int KT = 320 / 16;          // 20 ks per thread
    const int jp = tid & 7;
    const int g4 = (tid >> 3) & 3;
    const int kq = tid >> 5;              // 0..15
    const int rowA = g4 * 256 + sl * SLU + jp;
    const int rowB = rowA + 8;

    float wa[KT], wb[KT];
#pragma unroll
    for (int kk = 0; kk < KT; ++kk) {
        int k = kq * KT + kk;
        wa[kk] = (k < NF) ? wih[rowA * NF + k] : whh[rowA * NH + (k - NF)];
        wb[kk] = (k < NF) ? wih[rowB * NF + k] : whh[rowB * NH + (k - NF)];
    }
    if (tid < 64) {
        int gg = tid >> 4, jj = tid & 15, grow = gg * 256 + sl * SLU + jj;
        biasS[gg][jj] = bih[grow] + bhh[grow];
    }
    __syncthreads();

    const int fj = (tid & 127) >> 3, fb = tid & 7;   // finalize mapping (tid<128)
    float c_reg = 0.f;
    const bool isSent = (tid >= 128 && tid < 144);
    const int sj = isSent ? tid - 128 : 0;           // sentinel slice id

    for (int s = 0; s < TLEN; ++s) {
        const float* fsrc = feats + ((size_t)s * NG + g) * (NF * GS);
        float f0 = fsrc[tid];                        // 512 floats, 1/thread
        const float* hp   = h0 + ((size_t)(s & 7) * NG + g) * GSLAB + tid;
        const float* sent = h1 + ((size_t)((s + 6) & 7) * NG + g) * GSLAB + sj * 128;
        float hv[4];
        // ---- per-thread spin: exit as soon as OWN values are valid
        {
            bool again;
            do {
                again = false;
#pragma unroll
                for (int i = 0; i < 4; ++i) { hv[i] = HL(hp + i * 512); if (hv[i] != hv[i]) again = true; }
                if (s >= 3 && isSent) {
                    float sv = HL(sent); if (sv != sv) again = true;
                }
                if (again) __builtin_amdgcn_s_sleep(1);
            } while (again);
        }
        xs[tid] = f0;
#pragma unroll
        for (int i = 0; i < 4; ++i) xs[512 + i * 512 + tid] = hv[i];
        __syncthreads();                             // barrier A (collective validation)

        // gate GEMM, KT=20
        float4 aA0 = {0,0,0,0}, aA1 = {0,0,0,0}, aB0 = {0,0,0,0}, aB1 = {0,0,0,0};
        const float* xsk = xs + kq * (KT * GS);
#pragma unroll
        for (int kk = 0; kk < KT; ++kk) {
            float4 x0 = *(const float4*)(xsk + kk * GS);
            float4 x1 = *(const float4*)(xsk + kk * GS + 4);
            float wAv = wa[kk], wBv = wb[kk];
            FMA4(aA0, x0, wAv); FMA4(aA1, x1, wAv);
            FMA4(aB0, x0, wBv); FMA4(aB1, x1, wBv);
        }
        RED32(aA0); RED32(aA1); RED32(aB0); RED32(aB1);
        if ((tid & 32) == 0) {
            int gk = g4 * 8 + (tid >> 6);            // [gate][kq-pair 0..7]
            float4* r4 = (float4*)red;
            r4[gk * 32 + jp * 2 + 0]       = aA0;
            r4[gk * 32 + jp * 2 + 1]       = aA1;
            r4[gk * 32 + (jp + 8) * 2 + 0] = aB0;
            r4[gk * 32 + (jp + 8) * 2 + 1] = aB1;
        }
        __syncthreads();                             // barrier B

        if (tid < 128) {
            float gate[4];
#pragma unroll
            for (int gg = 0; gg < 4; ++gg) {
                float s0 = 0.f;
#pragma unroll
                for (int k2 = 0; k2 < 8; ++k2)
                    s0 += red[(gg * 8 + k2) * 128 + fj * 8 + fb];
                gate[gg] = s0 + biasS[gg][fj];
            }
            float i_ = sigf(gate[0]), f_ = sigf(gate[1]);
            float g_ = tanh_f(gate[2]), o_ = sigf(gate[3]);
            c_reg = fmaf(f_, c_reg, i_ * g_);
            float h = o_ * tanh_f(c_reg);
            HS(&h0[((size_t)((s + 1) & 7) * NG + g) * GSLAB + sl * 128 + tid], h);
            HS(&h0[((size_t)((s + 5) & 7) * NG + g) * GSLAB + sl * 128 + tid], poison_f());
        }
        // no end barrier needed: all xs reads precede barrier B
    }
}

// ---------------- layer-1 block (slice sl of group g), FC fused, 512 threads
__device__ __forceinline__ void run_l1(
    int g, int sl, int tid,
    const float* __restrict__ h0,
    const float* __restrict__ wih, const float* __restrict__ whh,
    const float* __restrict__ bih, const float* __restrict__ bhh,
    const float* __restrict__ fcw, const float* __restrict__ fcb,
    float* h1, float* __restrict__ out,
    float* xs, float* red, float (*biasS)[SLU])
{
    constexpr int KT = 512 / 16;          // 32 ks per thread
    const int jp = tid & 7;
    const int g4 = (tid >> 3) & 3;
    const int kq = tid >> 5;              // 0..15
    const int rowA = g4 * 256 + sl * SLU + jp;
    const int rowB = rowA + 8;

    float wa[KT], wb[KT];
#pragma unroll
    for (int kk = 0; kk < KT; ++kk) {
        int k = kq * KT + kk;
        wa[kk] = (k < NH) ? wih[rowA * NH + k] : whh[rowA * NH + (k - NH)];
        wb[kk] = (k < NH) ? wih[rowB * NH + k] : whh[rowB * NH + (k - NH)];
    }
    if (tid < 64) {
        int gg = tid >> 4, jj = tid & 15, grow = gg * 256 + sl * SLU + jj;
        biasS[gg][jj] = bih[grow] + bhh[grow];
    }
    __syncthreads();

    const int fj = (tid & 127) >> 3, fb = tid & 7;
    float c_reg = 0.f;
    const int fm = tid >> 4, fseg = tid & 15;     // FC mapping (tid<160)
    const int ffo = sl * 10 + (fm < 10 ? fm : 0);
    const int fo_o = ffo >> 3, fo_b = ffo & 7;

    for (int s = 0; s < TLEN; ++s) {
        // h0[s] in slot (s+1)&7 ; h1[s-1] in slot s&7
        const float* h0c = h0 + ((size_t)((s + 1) & 7) * NG + g) * GSLAB + tid;
        const float* h1p = h1 + ((size_t)(s & 7) * NG + g) * GSLAB + tid;
        float xr0[4], xr1[4];
        // ---- per-thread spin on own 8 values
        {
            bool again;
            do {
                again = false;
#pragma unroll
                for (int i = 0; i < 4; ++i) { xr0[i] = HL(h0c + i * 512); if (xr0[i] != xr0[i]) again = true; }
#pragma unroll
                for (int i = 0; i < 4; ++i) { xr1[i] = HL(h1p + i * 512); if (xr1[i] != xr1[i]) again = true; }
                if (again) __builtin_amdgcn_s_sleep(1);
            } while (again);
        }
#pragma unroll
        for (int i = 0; i < 4; ++i) xs[i * 512 + tid] = xr0[i];
#pragma unroll
        for (int i = 0; i < 4; ++i) xs[2048 + i * 512 + tid] = xr1[i];
        __syncthreads();                             // barrier A (collective validation)

        // gate GEMM, KT=32: kq 0..7 read h0 (xs[0,2048)), kq 8..15 read h1
        float4 aA0 = {0,0,0,0}, aA1 = {0,0,0,0}, aB0 = {0,0,0,0}, aB1 = {0,0,0,0};
        const float* xsk = xs + kq * (KT * GS);
#pragma unroll
        for (int kk = 0; kk < KT; ++kk) {
            float4 x0 = *(const float4*)(xsk + kk * GS);
            float4 x1 = *(const float4*)(xsk + kk * GS + 4);
            float wAv = wa[kk], wBv = wb[kk];
            FMA4(aA0, x0, wAv); FMA4(aA1, x1, wAv);
            FMA4(aB0, x0, wBv); FMA4(aB1, x1, wBv);
        }
        RED32(aA0); RED32(aA1); RED32(aB0); RED32(aB1);
        if ((tid & 32) == 0) {
            int gk = g4 * 8 + (tid >> 6);
            float4* r4 = (float4*)red;
            r4[gk * 32 + jp * 2 + 0]       = aA0;
            r4[gk * 32 + jp * 2 + 1]       = aA1;
            r4[gk * 32 + (jp + 8) * 2 + 0] = aB0;
            r4[gk * 32 + (jp + 8) * 2 + 1] = aB1;
        }
        __syncthreads();                             // barrier B

        if (tid < 128) {
            float gate[4];
#pragma unroll
            for (int gg = 0; gg < 4; ++gg) {
                float s0 = 0.f;
#pragma unroll
                for (int k2 = 0; k2 < 8; ++k2)
                    s0 += red[(gg * 8 + k2) * 128 + fj * 8 + fb];
                gate[gg] = s0 + biasS[gg][fj];
            }
            float i_ = sigf(gate[0]), f_ = sigf(gate[1]);
            float g_ = tanh_f(gate[2]), o_ = sigf(gate[3]);
            c_reg = fmaf(f_, c_reg, i_ * g_);
            float h = o_ * tanh_f(c_reg);
            HS(&h1[((size_t)((s + 1) & 7) * NG + g) * GSLAB + sl * 128 + tid], h);
            HS(&h1[((size_t)((s + 5) & 7) * NG + g) * GSLAB + sl * 128 + tid], poison_f());
        }

        // FC for t = s-1 from staged h1prev (xs[2048..]); shuffle-reduce
        if (s >= 1 && tid < 160) {
            const float* fwr = fcw + fo_o * NH;
            const float* xr = xs + NH * GS + fo_b;
            float p = 0.f;
#pragma unroll
            for (int i2 = 0; i2 < 16; ++i2) {
                int e = fseg * 16 + ((fseg + i2) & 15);   // bank rotation
                p = fmaf(fwr[e], xr[e * GS], p);
            }
#pragma unroll
            for (int d = 1; d < 16; d <<= 1) p += __shfl_xor(p, d, 16);
            if (fseg == 0)
                out[((size_t)(g * GS + fo_b) * NOUT + fo_o) * TLEN + (s - 1)] = p + fcb[fo_o];
        }
        __syncthreads();   // barrier C: protect xs (FC reads) before next staging
    }

    // epilogue FC for t = TLEN-1: validate-load h1[TLEN-1] (slot 0)
    {
        const float* hlast = h1 + ((size_t)(TLEN & 7) * NG + g) * GSLAB + tid;
        float xr1[4];
        bool again;
        do {
            again = false;
#pragma unroll
            for (int i = 0; i < 4; ++i) { xr1[i] = HL(hlast + i * 512); if (xr1[i] != xr1[i]) again = true; }
            if (again) __builtin_amdgcn_s_sleep(1);
        } while (again);
#pragma unroll
        for (int i = 0; i < 4; ++i) xs[2048 + i * 512 + tid] = xr1[i];
        __syncthreads();
        if (tid < 160) {
            const float* fwr = fcw + fo_o * NH;
            const float* xr = xs + NH * GS + fo_b;
            float p = 0.f;
#pragma unroll
            for (int i2 = 0; i2 < 16; ++i2) {
                int e = fseg * 16 + ((fseg + i2) & 15);
                p = fmaf(fwr[e], xr[e * GS], p);
            }
#pragma unroll
            for (int d = 1; d < 16; d <<= 1) p += __shfl_xor(p, d, 16);
            if (fseg == 0)
                out[((size_t)(g * GS + fo_b) * NOUT + fo_o) * TLEN + (TLEN - 1)] = p + fcb[fo_o];
        }
    }
}

// Grid: 256 blocks x 512 threads, plain launch. Block (g, r): r<16 -> L0 slice r;
// r>=16 -> L1 slice r-16. 128-VGPR cap (512-thread block) is the DESIGN budget.
__global__ __launch_bounds__(512, 1) void lstm_kernel(
    const float* __restrict__ feats,
    const float* __restrict__ wih0, const float* __restrict__ whh0,
    const float* __restrict__ bih0, const float* __restrict__ bhh0,
    const float* __restrict__ wih1, const float* __restrict__ whh1,
    const float* __restrict__ bih1, const float* __restrict__ bhh1,
    const float* __restrict__ fcw,  const float* __restrict__ fcb,
    float* h0h, float* h1h, float* __restrict__ out)
{
    __shared__ float xs[512 * GS];        // 16 KB
    __shared__ float red[32 * 128];       // 16 KB (8 wave-partials x 4 gates)
    __shared__ float biasS[4][SLU];
    const int blk = blockIdx.x, tid = threadIdx.x;
    const int g = blk >> 5, r = blk & 31;

    if (r < 16)
        run_l0(g, r, tid, feats, wih0, whh0, bih0, bhh0,
               h0h, h1h, xs, red, biasS);
    else
        run_l1(g, r - 16, tid, h0h, wih1, whh1, bih1, bhh1,
               fcw, fcb, h1h, out, xs, red, biasS);
}

extern "C" void kernel_launch(void* const* d_in, const int* in_sizes, int n_in,
                              void* d_out, int out_size, void* d_ws, size_t ws_size,
                              hipStream_t stream) {
    (void)in_sizes; (void)n_in; (void)out_size; (void)ws_size;
    const float* x      = (const float*)d_in[0];
    const float* conv_w = (const float*)d_in[1];
    const float* conv_b = (const float*)d_in[2];
    const float* gamma  = (const float*)d_in[3];
    const float* beta   = (const float*)d_in[4];
    const float* wih0   = (const float*)d_in[5];
    const float* whh0   = (const float*)d_in[6];
    const float* bih0   = (const float*)d_in[7];
    const float* bhh0   = (const float*)d_in[8];
    const float* wih1   = (const float*)d_in[9];
    const float* whh1   = (const float*)d_in[10];
    const float* bih1   = (const float*)d_in[11];
    const float* bhh1   = (const float*)d_in[12];
    const float* fcw    = (const float*)d_in[13];
    const float* fcb    = (const float*)d_in[14];
    float* out = (float*)d_out;

    char* ws = (char*)d_ws;
    const size_t H_RING  = (size_t)NSLOT * NG * GSLAB * 4;       // 524,288 B each
    const size_t SLOT0_B = (size_t)NG * GSLAB * 4;               // 65,536 B
    const size_t FEATS_B = (size_t)TLEN * NG * NF * GS * 4;      // 33,554,432 B

    float* h0h      = (float*)(ws);
    float* h1h      = (float*)(ws + H_RING);
    float* feats    = (float*)(ws + 2 * H_RING);
    float* partials = (float*)(ws + 2 * H_RING + FEATS_B);

    // Poison rings with 0xFF (= NaN), then zero slot 0 (h[-1]).
    (void)hipMemsetAsync(h0h, 0xFF, H_RING, stream);
    (void)hipMemsetAsync(h1h, 0xFF, H_RING, stream);
    (void)hipMemsetAsync(h0h, 0x00, SLOT0_B, stream);
    (void)hipMemsetAsync(h1h, 0x00, SLOT0_B, stream);

    conv_stats_kernel<<<dim3(256), dim3(256), 0, stream>>>(x, conv_w, conv_b, partials);
    conv_bn_feats_kernel<<<dim3(2048), dim3(256), 0, stream>>>(
        x, conv_w, conv_b, gamma, beta, partials, feats);

    lstm_kernel<<<dim3(256), dim3(512), 0, stream>>>(
        feats, wih0, whh0, bih0, bhh0, wih1, whh1, bih1, bhh1,
        fcw, fcb, h0h, h1h, out);
}

// Round 17
// 11232.830 us; speedup vs baseline: 3.2515x; 1.0562x over previous
//
#include <hip/hip_runtime.h>

#define TLEN 2048
#define NB   64
#define NH   256
#define NF   64
#define NCIN 16
#define NOUT 20
#define NG   8              // batch groups (sync domains)
#define GS   8              // samples per group
#define SLU  16             // hidden units per slice (block)
#define GSLAB (NH * GS)     // 2048 floats: one group's h slab [unit][sample]
#define NSLOT 8             // h ring depth

// LLC-coherent (sc1) helpers — the proven exchange medium (r3..r16).
#define HL(p)    __hip_atomic_load((p),      __ATOMIC_RELAXED, __HIP_MEMORY_SCOPE_AGENT)
#define HS(p, v) __hip_atomic_store((p), (v), __ATOMIC_RELAXED, __HIP_MEMORY_SCOPE_AGENT)

__device__ __forceinline__ float poison_f() { return __uint_as_float(0xFFFFFFFFu); }

__device__ __forceinline__ float sigf(float x) { return 1.0f / (1.0f + __expf(-x)); }
__device__ __forceinline__ float tanh_f(float x) {
    x = fminf(fmaxf(x, -15.0f), 15.0f);
    float e = __expf(2.0f * x);
    return (e - 1.0f) / (e + 1.0f);
}

// NOTE: parameter must NOT be named `w` — `xv.w` would get macro-substituted.
#define FMA4(acc, xv, ww) do { \
    acc.x = fmaf(xv.x, (ww), acc.x); \
    acc.y = fmaf(xv.y, (ww), acc.y); \
    acc.z = fmaf(xv.z, (ww), acc.z); \
    acc.w = fmaf(xv.w, (ww), acc.w); } while (0)

#define RED32(vv) do { \
    vv.x += __shfl_xor(vv.x, 32); vv.y += __shfl_xor(vv.y, 32); \
    vv.z += __shfl_xor(vv.z, 32); vv.w += __shfl_xor(vv.w, 32); } while (0)

// wave-local LDS fence: stage (ds_write) -> GEMM (ds_read) within one wave.
#define WAVE_LDS_FENCE() asm volatile("s_waitcnt lgkmcnt(0)" ::: "memory")

// ---------------- Pass A: conv + relu, per-(f, t-quarter) partial sums for BN stats
__global__ __launch_bounds__(256) void conv_stats_kernel(
    const float* __restrict__ x, const float* __restrict__ cw, const float* __restrict__ cb,
    float* __restrict__ partials)
{
    const int blk = blockIdx.x;          // 256 blocks
    const int f = blk >> 2, tq = blk & 3;
    const int tid = threadIdx.x;

    float w[NCIN][3];
#pragma unroll
    for (int c = 0; c < NCIN; ++c) {
        w[c][0] = cw[(f * NCIN + c) * 3 + 0];
        w[c][1] = cw[(f * NCIN + c) * 3 + 1];
        w[c][2] = cw[(f * NCIN + c) * 3 + 2];
    }
    const float bias = cb[f];
    float s = 0.f, s2 = 0.f;

    for (int i = 0; i < 128; ++i) {
        int idx = tq * 32768 + i * 256 + tid;   // (B*T)/4 elements per block
        int b = idx >> 11;
        int t = idx & 2047;
        const float* xb = x + (size_t)b * NCIN * TLEN;
        float acc = bias;
#pragma unroll
        for (int c = 0; c < NCIN; ++c) {
            const float* xc = xb + (size_t)c * TLEN + t;
            float xm = (t > 0)        ? xc[-1] : 0.f;
            float x0 = xc[0];
            float xp = (t < TLEN - 1) ? xc[1]  : 0.f;
            acc = fmaf(xm, w[c][0], acc);
            acc = fmaf(x0, w[c][1], acc);
            acc = fmaf(xp, w[c][2], acc);
        }
        float y = fmaxf(acc, 0.f);
        s += y; s2 = fmaf(y, y, s2);
    }

    __shared__ float rs[256], rs2[256];
    rs[tid] = s; rs2[tid] = s2;
    __syncthreads();
    for (int off = 128; off > 0; off >>= 1) {
        if (tid < off) { rs[tid] += rs[tid + off]; rs2[tid] += rs2[tid + off]; }
        __syncthreads();
    }
    if (tid == 0) {
        partials[(f * 4 + tq) * 2 + 0] = rs[0];
        partials[(f * 4 + tq) * 2 + 1] = rs2[0];
    }
}

// ---------------- Pass B: conv + relu + BN affine, write feats[t][g][f][bl]
__global__ __launch_bounds__(256) void conv_bn_feats_kernel(
    const float* __restrict__ x, const float* __restrict__ cw, const float* __restrict__ cb,
    const float* __restrict__ gamma, const float* __restrict__ beta,
    const float* __restrict__ partials, float* __restrict__ feats)
{
    const int t = blockIdx.x;            // 2048 blocks
    const int tid = threadIdx.x;
    const int b = tid & 63, fq = tid >> 6;

    __shared__ float sc[NF], sh[NF];
    if (tid < NF) {
        int f = tid;
        float s = 0.f, s2 = 0.f;
        for (int q = 0; q < 4; ++q) {
            s  += partials[(f * 4 + q) * 2 + 0];
            s2 += partials[(f * 4 + q) * 2 + 1];
        }
        const float inv_n = 1.0f / ((float)NB * (float)TLEN);
        float mean = s * inv_n;
        float var  = s2 * inv_n - mean * mean;
        float iv   = rsqrtf(var + 1e-5f);
        float scale = gamma[f] * iv;
        sc[f] = scale;
        sh[f] = beta[f] - mean * scale;
    }
    __syncthreads();

    float xr[NCIN][3];
    const float* xb = x + (size_t)b * NCIN * TLEN;
#pragma unroll
    for (int c = 0; c < NCIN; ++c) {
        const float* xc = xb + (size_t)c * TLEN + t;
        xr[c][0] = (t > 0)        ? xc[-1] : 0.f;
        xr[c][1] = xc[0];
        xr[c][2] = (t < TLEN - 1) ? xc[1]  : 0.f;
    }

    float* ft = feats + (size_t)t * (NG * NF * GS);
    for (int fi = 0; fi < 16; ++fi) {
        int f = fq * 16 + fi;
        float acc = cb[f];
#pragma unroll
        for (int c = 0; c < NCIN; ++c) {
            acc = fmaf(xr[c][0], cw[(f * NCIN + c) * 3 + 0], acc);
            acc = fmaf(xr[c][1], cw[(f * NCIN + c) * 3 + 1], acc);
            acc = fmaf(xr[c][2], cw[(f * NCIN + c) * 3 + 2], acc);
        }
        float y = fmaxf(acc, 0.f);
        ft[((b >> 3) * NF + f) * GS + (b & 7)] = fmaf(y, sc[f], sh[f]);
    }
}

// =====================================================================
// r16 structure + WAVE-LOCAL staging (r17): wave w stages exactly the xs
// region its own GEMM reads (L0: [w*320,+320), L1: [w*512,+512)), spins only
// on the slab values IT consumes, then proceeds to GEMM with just a wave
// LDS fence — NO pre-GEMM block barrier. Early waves compute while the
// wave owning late data still spins (wait overlapped with GEMM).
// Barrier B (pre cross-wave reduce-read) now carries collective validation:
// all waves passed their spins before any finalize/publish/poison -> every
// r10/r15 poison-distance argument holds. L0 adds end-of-loop barrier C to
// protect red[] (was barrier A's job); L1 keeps barrier C for xs/FC.
// Protocol: h[m] in slot (m+1)&7; rings pre-poisoned; slot0 zeros;
//   at step s both layers poison h[s-4]; L0 sentinel on h1[s-3].
// =====================================================================

// ---------------- layer-0 block (slice sl of group g), 512 threads
__device__ __forceinline__ void run_l0(
    int g, int sl, int tid,
    const float* __restrict__ feats,
    const float* __restrict__ wih, const float* __restrict__ whh,
    const float* __restrict__ bih, const float* __restrict__ bhh,
    float* h0, const float* h1,
    float* xs, float* red, float (*biasS)[SLU])
{
    constexpr int KT = 320 / 16;          // 20 ks per thread
    const int jp = tid & 7;
    const int g4 = (tid >> 3) & 3;
    const int kq = tid >> 5;              // 0..15
    const int wv = tid >> 6;              // wave 0..7
    const int ln = tid & 63;
    const int rowA = g4 * 256 + sl * SLU + jp;
    const int rowB = rowA + 8;

    float wa[KT], wb[KT];
#pragma unroll
    for (int kk = 0; kk < KT; ++kk) {
        int k = kq * KT + kk;
        wa[kk] = (k < NF) ? wih[rowA * NF + k] : whh[rowA * NH + (k - NF)];
        wb[kk] = (k < NF) ? wih[rowB * NF + k] : whh[rowB * NH + (k - NF)];
    }
    if (tid < 64) {
        int gg = tid >> 4, jj = tid & 15, grow = gg * 256 + sl * SLU + jj;
        biasS[gg][jj] = bih[grow] + bhh[grow];
    }
    __syncthreads();

    const int fj = (tid & 127) >> 3, fb = tid & 7;   // finalize mapping (tid<128)
    float c_reg = 0.f;
    const bool isSent = (tid >= 128 && tid < 144);
    const int sj = isSent ? tid - 128 : 0;           // sentinel slice id

    for (int s = 0; s < TLEN; ++s) {
        const float* fsrc = feats + ((size_t)s * NG + g) * (NF * GS);
        const float* h0slab = h0 + ((size_t)(s & 7) * NG + g) * GSLAB;        // h0[s-1]
        const float* sent   = h1 + ((size_t)((s + 6) & 7) * NG + g) * GSLAB + sj * 128;

        // ---- wave-local stage: wave wv owns xs[wv*320, +320); 5 values/lane
        float v[5];
#pragma unroll
        for (int i = 0; i < 5; ++i) {
            int j = wv * 320 + i * 64 + ln;
            v[i] = (j < 512) ? fsrc[j] : HL(h0slab + (j - 512));
        }
        // per-thread spin on own h values (+ sentinel for tid 128..143)
        {
            bool again;
            do {
                again = false;
#pragma unroll
                for (int i = 0; i < 5; ++i) {
                    int j = wv * 320 + i * 64 + ln;
                    if (j >= 512 && v[i] != v[i]) {
                        v[i] = HL(h0slab + (j - 512));
                        if (v[i] != v[i]) again = true;
                    }
                }
                if (s >= 3 && isSent) {
                    float sv = HL(sent); if (sv != sv) again = true;
                }
                if (again) __builtin_amdgcn_s_sleep(1);
            } while (again);
        }
#pragma unroll
        for (int i = 0; i < 5; ++i) xs[wv * 320 + i * 64 + ln] = v[i];
        WAVE_LDS_FENCE();                 // same-wave stage->read, no block barrier

        // gate GEMM, KT=20 (reads only this wave's region)
        float4 aA0 = {0,0,0,0}, aA1 = {0,0,0,0}, aB0 = {0,0,0,0}, aB1 = {0,0,0,0};
        const float* xsk = xs + kq * (KT * GS);
#pragma unroll
        for (int kk = 0; kk < KT; ++kk) {
            float4 x0 = *(const float4*)(xsk + kk * GS);
            float4 x1 = *(const float4*)(xsk + kk * GS + 4);
            float wAv = wa[kk], wBv = wb[kk];
            FMA4(aA0, x0, wAv); FMA4(aA1, x1, wAv);
            FMA4(aB0, x0, wBv); FMA4(aB1, x1, wBv);
        }
        RED32(aA0); RED32(aA1); RED32(aB0); RED32(aB1);
        if ((tid & 32) == 0) {
            int gk = g4 * 8 + (tid >> 6);            // [gate][kq-pair 0..7]
            float4* r4 = (float4*)red;
            r4[gk * 32 + jp * 2 + 0]       = aA0;
            r4[gk * 32 + jp * 2 + 1]       = aA1;
            r4[gk * 32 + (jp + 8) * 2 + 0] = aB0;
            r4[gk * 32 + (jp + 8) * 2 + 1] = aB1;
        }
        __syncthreads();                             // barrier B (collective validation)

        if (tid < 128) {
            float gate[4];
#pragma unroll
            for (int gg = 0; gg < 4; ++gg) {
                float s0 = 0.f;
#pragma unroll
                for (int k2 = 0; k2 < 8; ++k2)
                    s0 += red[(gg * 8 + k2) * 128 + fj * 8 + fb];
                gate[gg] = s0 + biasS[gg][fj];
            }
            float i_ = sigf(gate[0]), f_ = sigf(gate[1]);
            float g_ = tanh_f(gate[2]), o_ = sigf(gate[3]);
            c_reg = fmaf(f_, c_reg, i_ * g_);
            float h = o_ * tanh_f(c_reg);
            HS(&h0[((size_t)((s + 1) & 7) * NG + g) * GSLAB + sl * 128 + tid], h);
            HS(&h0[((size_t)((s + 5) & 7) * NG + g) * GSLAB + sl * 128 + tid], poison_f());
        }
        __syncthreads();                             // barrier C: protect red[] reuse
    }
}

// ---------------- layer-1 block (slice sl of group g), FC fused, 512 threads
__device__ __forceinline__ void run_l1(
    int g, int sl, int tid,
    const float* __restrict__ h0,
    const float* __restrict__ wih, const float* __restrict__ whh,
    const float* __restrict__ bih, const float* __restrict__ bhh,
    const float* __restrict__ fcw, const float* __restrict__ fcb,
    float* h1, float* __restrict__ out,
    float* xs, float* red, float (*biasS)[SLU])
{
    constexpr int KT = 512 / 16;          // 32 ks per thread
    const int jp = tid & 7;
    const int g4 = (tid >> 3) & 3;
    const int kq = tid >> 5;              // 0..15
    const int wv = tid >> 6;              // wave 0..7
    const int ln = tid & 63;
    const int rowA = g4 * 256 + sl * SLU + jp;
    const int rowB = rowA + 8;

    float wa[KT], wb[KT];
#pragma unroll
    for (int kk = 0; kk < KT; ++kk) {
        int k = kq * KT + kk;
        wa[kk] = (k < NH) ? wih[rowA * NH + k] : whh[rowA * NH + (k - NH)];
        wb[kk] = (k < NH) ? wih[rowB * NH + k] : whh[rowB * NH + (k - NH)];
    }
    if (tid < 64) {
        int gg = tid >> 4, jj = tid & 15, grow = gg * 256 + sl * SLU + jj;
        biasS[gg][jj] = bih[grow] + bhh[grow];
    }
    __syncthreads();

    const int fj = (tid & 127) >> 3, fb = tid & 7;
    float c_reg = 0.f;
    const int fm = tid >> 4, fseg = tid & 15;     // FC mapping (tid<160)
    const int ffo = sl * 10 + (fm < 10 ? fm : 0);
    const int fo_o = ffo >> 3, fo_b = ffo & 7;

    for (int s = 0; s < TLEN; ++s) {
        const float* h0slab = h0 + ((size_t)((s + 1) & 7) * NG + g) * GSLAB;  // h0[s]
        const float* h1slab = h1 + ((size_t)(s & 7) * NG + g) * GSLAB;        // h1[s-1]

        // ---- wave-local stage: wave wv owns xs[wv*512, +512); 8 values/lane
        float v[8];
#pragma unroll
        for (int i = 0; i < 8; ++i) {
            int j = wv * 512 + i * 64 + ln;
            v[i] = (j < 2048) ? HL(h0slab + j) : HL(h1slab + (j - 2048));
        }
        {
            bool again;
            do {
                again = false;
#pragma unroll
                for (int i = 0; i < 8; ++i) {
                    if (v[i] != v[i]) {
                        int j = wv * 512 + i * 64 + ln;
                        v[i] = (j < 2048) ? HL(h0slab + j) : HL(h1slab + (j - 2048));
                        if (v[i] != v[i]) again = true;
                    }
                }
                if (again) __builtin_amdgcn_s_sleep(1);
            } while (again);
        }
#pragma unroll
        for (int i = 0; i < 8; ++i) xs[wv * 512 + i * 64 + ln] = v[i];
        WAVE_LDS_FENCE();                 // same-wave stage->read

        // gate GEMM, KT=32 (reads only this wave's region)
        float4 aA0 = {0,0,0,0}, aA1 = {0,0,0,0}, aB0 = {0,0,0,0}, aB1 = {0,0,0,0};
        const float* xsk = xs + kq * (KT * GS);
#pragma unroll
        for (int kk = 0; kk < KT; ++kk) {
            float4 x0 = *(const float4*)(xsk + kk * GS);
            float4 x1 = *(const float4*)(xsk + kk * GS + 4);
            float wAv = wa[kk], wBv = wb[kk];
            FMA4(aA0, x0, wAv); FMA4(aA1, x1, wAv);
            FMA4(aB0, x0, wBv); FMA4(aB1, x1, wBv);
        }
        RED32(aA0); RED32(aA1); RED32(aB0); RED32(aB1);
        if ((tid & 32) == 0) {
            int gk = g4 * 8 + (tid >> 6);
            float4* r4 = (float4*)red;
            r4[gk * 32 + jp * 2 + 0]       = aA0;
            r4[gk * 32 + jp * 2 + 1]       = aA1;
            r4[gk * 32 + (jp + 8) * 2 + 0] = aB0;
            r4[gk * 32 + (jp + 8) * 2 + 1] = aB1;
        }
        __syncthreads();                             // barrier B (collective validation)

        if (tid < 128) {
            float gate[4];
#pragma unroll
            for (int gg = 0; gg < 4; ++gg) {
                float s0 = 0.f;
#pragma unroll
                for (int k2 = 0; k2 < 8; ++k2)
                    s0 += red[(gg * 8 + k2) * 128 + fj * 8 + fb];
                gate[gg] = s0 + biasS[gg][fj];
            }
            float i_ = sigf(gate[0]), f_ = sigf(gate[1]);
            float g_ = tanh_f(gate[2]), o_ = sigf(gate[3]);
            c_reg = fmaf(f_, c_reg, i_ * g_);
            float h = o_ * tanh_f(c_reg);
            HS(&h1[((size_t)((s + 1) & 7) * NG + g) * GSLAB + sl * 128 + tid], h);
            HS(&h1[((size_t)((s + 5) & 7) * NG + g) * GSLAB + sl * 128 + tid], poison_f());
        }

        // FC for t = s-1 from staged h1prev (xs[2048..4096), complete at barrier B)
        if (s >= 1 && tid < 160) {
            const float* fwr = fcw + fo_o * NH;
            const float* xr = xs + NH * GS + fo_b;
            float p = 0.f;
#pragma unroll
            for (int i2 = 0; i2 < 16; ++i2) {
                int e = fseg * 16 + ((fseg + i2) & 15);   // bank rotation
                p = fmaf(fwr[e], xr[e * GS], p);
            }
#pragma unroll
            for (int d = 1; d < 16; d <<= 1) p += __shfl_xor(p, d, 16);
            if (fseg == 0)
                out[((size_t)(g * GS + fo_b) * NOUT + fo_o) * TLEN + (s - 1)] = p + fcb[fo_o];
        }
        __syncthreads();   // barrier C: xs (FC reads) + red[] protected before next step
    }

    // epilogue FC for t = TLEN-1: validate-load h1[TLEN-1] (slot 0)
    {
        const float* hlast = h1 + ((size_t)(TLEN & 7) * NG + g) * GSLAB + tid;
        float xr1[4];
        bool again;
        do {
            again = false;
#pragma unroll
            for (int i = 0; i < 4; ++i) { xr1[i] = HL(hlast + i * 512); if (xr1[i] != xr1[i]) again = true; }
            if (again) __builtin_amdgcn_s_sleep(1);
        } while (again);
#pragma unroll
        for (int i = 0; i < 4; ++i) xs[2048 + i * 512 + tid] = xr1[i];
        __syncthreads();
        if (tid < 160) {
            const float* fwr = fcw + fo_o * NH;
            const float* xr = xs + NH * GS + fo_b;
            float p = 0.f;
#pragma unroll
            for (int i2 = 0; i2 < 16; ++i2) {
                int e = fseg * 16 + ((fseg + i2) & 15);
                p = fmaf(fwr[e], xr[e * GS], p);
            }
#pragma unroll
            for (int d = 1; d < 16; d <<= 1) p += __shfl_xor(p, d, 16);
            if (fseg == 0)
                out[((size_t)(g * GS + fo_b) * NOUT + fo_o) * TLEN + (TLEN - 1)] = p + fcb[fo_o];
        }
    }
}

// Grid: 256 blocks x 512 threads, plain launch. Block (g, r): r<16 -> L0 slice r;
// r>=16 -> L1 slice r-16. 128-VGPR cap (512-thread block) is the DESIGN budget.
__global__ __launch_bounds__(512, 1) void lstm_kernel(
    const float* __restrict__ feats,
    const float* __restrict__ wih0, const float* __restrict__ whh0,
    const float* __restrict__ bih0, const float* __restrict__ bhh0,
    const float* __restrict__ wih1, const float* __restrict__ whh1,
    const float* __restrict__ bih1, const float* __restrict__ bhh1,
    const float* __restrict__ fcw,  const float* __restrict__ fcb,
    float* h0h, float* h1h, float* __restrict__ out)
{
    __shared__ float xs[512 * GS];        // 16 KB
    __shared__ float red[32 * 128];       // 16 KB (8 wave-partials x 4 gates)
    __shared__ float biasS[4][SLU];
    const int blk = blockIdx.x, tid = threadIdx.x;
    const int g = blk >> 5, r = blk & 31;

    if (r < 16)
        run_l0(g, r, tid, feats, wih0, whh0, bih0, bhh0,
               h0h, h1h, xs, red, biasS);
    else
        run_l1(g, r - 16, tid, h0h, wih1, whh1, bih1, bhh1,
               fcw, fcb, h1h, out, xs, red, biasS);
}

extern "C" void kernel_launch(void* const* d_in, const int* in_sizes, int n_in,
                              void* d_out, int out_size, void* d_ws, size_t ws_size,
                              hipStream_t stream) {
    (void)in_sizes; (void)n_in; (void)out_size; (void)ws_size;
    const float* x      = (const float*)d_in[0];
    const float* conv_w = (const float*)d_in[1];
    const float* conv_b = (const float*)d_in[2];
    const float* gamma  = (const float*)d_in[3];
    const float* beta   = (const float*)d_in[4];
    const float* wih0   = (const float*)d_in[5];
    const float* whh0   = (const float*)d_in[6];
    const float* bih0   = (const float*)d_in[7];
    const float* bhh0   = (const float*)d_in[8];
    const float* wih1   = (const float*)d_in[9];
    const float* whh1   = (const float*)d_in[10];
    const float* bih1   = (const float*)d_in[11];
    const float* bhh1   = (const float*)d_in[12];
    const float* fcw    = (const float*)d_in[13];
    const float* fcb    = (const float*)d_in[14];
    float* out = (float*)d_out;

    char* ws = (char*)d_ws;
    const size_t H_RING  = (size_t)NSLOT * NG * GSLAB * 4;       // 524,288 B each
    const size_t SLOT0_B = (size_t)NG * GSLAB * 4;               // 65,536 B
    const size_t FEATS_B = (size_t)TLEN * NG * NF * GS * 4;      // 33,554,432 B

    float* h0h      = (float*)(ws);
    float* h1h      = (float*)(ws + H_RING);
    float* feats    = (float*)(ws + 2 * H_RING);
    float* partials = (float*)(ws + 2 * H_RING + FEATS_B);

    // Poison rings with 0xFF (= NaN), then zero slot 0 (h[-1]).
    (void)hipMemsetAsync(h0h, 0xFF, H_RING, stream);
    (void)hipMemsetAsync(h1h, 0xFF, H_RING, stream);
    (void)hipMemsetAsync(h0h, 0x00, SLOT0_B, stream);
    (void)hipMemsetAsync(h1h, 0x00, SLOT0_B, stream);

    conv_stats_kernel<<<dim3(256), dim3(256), 0, stream>>>(x, conv_w, conv_b, partials);
    conv_bn_feats_kernel<<<dim3(2048), dim3(256), 0, stream>>>(
        x, conv_w, conv_b, gamma, beta, partials, feats);

    lstm_kernel<<<dim3(256), dim3(512), 0, stream>>>(
        feats, wih0, whh0, bih0, bhh0, wih1, whh1, bih1, bhh1,
        fcw, fcb, h0h, h1h, out);
}